// Round 1
// baseline (828.921 us; speedup 1.0000x reference)
//
#include <hip/hip_runtime.h>
#include <math.h>

#define NA 16
#define NBEAM 12
#define NUSER 8

// ws layout: [0 .. 1535]  : steering table, 12 beams x (16 cos | 16 sin) floats
//            [1536..1543] : double accumulator
#define ACC_OFFSET 1536

__global__ void mtl_angles_kernel(const float* __restrict__ Hc_r, const float* __restrict__ Hc_i,
                                  const float* __restrict__ Hs_r, const float* __restrict__ Hs_i,
                                  float* __restrict__ table, double* __restrict__ acc) {
    int t = threadIdx.x;
    if (t == 0) *acc = 0.0;          // zero the reduction accumulator (ws is poisoned 0xAA)
    if (t >= NBEAM) return;

    const float* re;
    const float* im;
    if (t < NUSER) { re = Hc_r + t * NA;           im = Hc_i + t * NA; }          // Hc[0, t, :]
    else           { re = Hs_r + (t - NUSER) * NA; im = Hs_i + (t - NUSER) * NA; } // Hs[0, t, :]

    const float PI_F   = 3.14159265358979323846f;
    const float TWO_PI = 6.28318530717958647692f;

    float ph[NA];
    #pragma unroll
    for (int n = 0; n < NA; ++n) ph[n] = atan2f(im[n], re[n]);

    // unwrapped[0]=0; unwrapped[n]=cumsum of wrapped diffs. n_c = n - 7.5, sum(n_c^2)=340.
    float unw = 0.f, dotsum = 0.f;
    #pragma unroll
    for (int n = 1; n < NA; ++n) {
        float pd = ph[n] - ph[n - 1];
        float x  = pd + PI_F;
        float m  = fmodf(x, TWO_PI);       // python % has sign of divisor
        if (m < 0.f) m += TWO_PI;
        pd = m - PI_F;
        unw += pd;
        dotsum += unw * ((float)n - 7.5f);
    }
    float slope = dotsum / 340.0f;
    float sin_theta = slope / PI_F;        // slope * WAVELENGTH / (2*pi*D), D=0.5, lambda=1
    sin_theta = fminf(1.0f, fmaxf(-1.0f, sin_theta));
    // angle = -asin(sin_theta); steering uses sin(angle) = -sin_theta
    float st = -sin_theta;

    #pragma unroll
    for (int n = 0; n < NA; ++n) {
        float phase = PI_F * st * (float)n;    // 2*pi*D*st*n/lambda = pi*st*n
        table[t * 2 * NA + n]      = cosf(phase);
        table[t * 2 * NA + NA + n] = sinf(phase);
    }
}

__device__ __forceinline__ float dot4(float4 a, float4 b) {
    return a.x * b.x + a.y * b.y + a.z * b.z + a.w * b.w;
}

__global__ __launch_bounds__(256) void mtl_gains_kernel(const float* __restrict__ W,
                                                        const float* __restrict__ table,
                                                        double* __restrict__ acc, int rows) {
    __shared__ float sh[NBEAM * 2 * NA];   // 384 floats
    for (int i = threadIdx.x; i < NBEAM * 2 * NA; i += blockDim.x) sh[i] = table[i];
    __syncthreads();

    float local = 0.f;
    int stride = gridDim.x * blockDim.x;
    for (int row = blockIdx.x * blockDim.x + threadIdx.x; row < rows; row += stride) {
        const float4* wp = (const float4*)(W + (size_t)row * 32);
        float4 wr0 = wp[0], wr1 = wp[1], wr2 = wp[2], wr3 = wp[3];
        float4 wi0 = wp[4], wi1 = wp[5], wi2 = wp[6], wi3 = wp[7];

        float minU = 3.4e38f, sumU = 0.f, sumT = 0.f;
        #pragma unroll
        for (int j = 0; j < NBEAM; ++j) {
            const float4* tc = (const float4*)(sh + j * 32);
            float4 c0 = tc[0], c1 = tc[1], c2 = tc[2], c3 = tc[3];
            float4 s0 = tc[4], s1 = tc[5], s2 = tc[6], s3 = tc[7];
            float re = dot4(wr0, c0) + dot4(wr1, c1) + dot4(wr2, c2) + dot4(wr3, c3)
                     + dot4(wi0, s0) + dot4(wi1, s1) + dot4(wi2, s2) + dot4(wi3, s3);
            float im = dot4(wi0, c0) + dot4(wi1, c1) + dot4(wi2, c2) + dot4(wi3, c3)
                     - dot4(wr0, s0) - dot4(wr1, s1) - dot4(wr2, s2) - dot4(wr3, s3);
            float g = sqrtf(re * re + im * im);
            if (j < NUSER) { minU = fminf(minU, g); sumU += g; }
            else           { sumT += g; }
        }
        // comm = -rho*2.5*(min + 0.1*sum) = -2*(min+0.1*sum); sens = -(1-rho)*sumT/4 = -0.05*sumT
        local += -2.0f * (minU + 0.1f * sumU) - 0.05f * sumT;
    }

    // wave reduce (64 lanes)
    #pragma unroll
    for (int off = 32; off > 0; off >>= 1) local += __shfl_down(local, off);
    __shared__ float wsum[4];
    int lane = threadIdx.x & 63, wid = threadIdx.x >> 6;
    if (lane == 0) wsum[wid] = local;
    __syncthreads();
    if (threadIdx.x == 0) {
        float b = wsum[0] + wsum[1] + wsum[2] + wsum[3];
        atomicAdd(acc, (double)b);
    }
}

__global__ void mtl_finalize_kernel(const double* __restrict__ acc, float* __restrict__ out, int rows) {
    if (threadIdx.x == 0) out[0] = (float)(*acc / (double)rows);
}

extern "C" void kernel_launch(void* const* d_in, const int* in_sizes, int n_in,
                              void* d_out, int out_size, void* d_ws, size_t ws_size,
                              hipStream_t stream) {
    const float* W    = (const float*)d_in[0];
    const float* Hc_r = (const float*)d_in[1];
    const float* Hc_i = (const float*)d_in[2];
    const float* Hs_r = (const float*)d_in[3];
    const float* Hs_i = (const float*)d_in[4];
    float* out = (float*)d_out;

    int rows = in_sizes[0] / (2 * NA);   // 2,000,000
    float*  table = (float*)d_ws;
    double* acc   = (double*)((char*)d_ws + ACC_OFFSET);

    mtl_angles_kernel<<<1, 64, 0, stream>>>(Hc_r, Hc_i, Hs_r, Hs_i, table, acc);

    const int ROWS_PER_THREAD = 4;
    int blocks = (rows + 256 * ROWS_PER_THREAD - 1) / (256 * ROWS_PER_THREAD);
    mtl_gains_kernel<<<blocks, 256, 0, stream>>>(W, table, acc, rows);

    mtl_finalize_kernel<<<1, 64, 0, stream>>>(acc, out, rows);
}

// Round 2
// 366.413 us; speedup vs baseline: 2.2623x; 2.2623x over previous
//
#include <hip/hip_runtime.h>
#include <math.h>

#define NA 16
#define NBEAM 12
#define NUSER 8

// ws layout: [0 .. 1535]  : steering table, 12 beams x (16 cos | 16 sin) floats
//            [1536..1543] : double accumulator
#define ACC_OFFSET 1536

__global__ void mtl_angles_kernel(const float* __restrict__ Hc_r, const float* __restrict__ Hc_i,
                                  const float* __restrict__ Hs_r, const float* __restrict__ Hs_i,
                                  float* __restrict__ table, double* __restrict__ acc) {
    int t = threadIdx.x;
    if (t == 0) *acc = 0.0;          // zero the reduction accumulator (ws is poisoned 0xAA)
    if (t >= NBEAM) return;

    const float* re;
    const float* im;
    if (t < NUSER) { re = Hc_r + t * NA;           im = Hc_i + t * NA; }          // Hc[0, t, :]
    else           { re = Hs_r + (t - NUSER) * NA; im = Hs_i + (t - NUSER) * NA; } // Hs[0, t, :]

    const float PI_F   = 3.14159265358979323846f;
    const float TWO_PI = 6.28318530717958647692f;

    float ph[NA];
    #pragma unroll
    for (int n = 0; n < NA; ++n) ph[n] = atan2f(im[n], re[n]);

    // unwrapped[0]=0; unwrapped[n]=cumsum of wrapped diffs. n_c = n - 7.5, sum(n_c^2)=340.
    float unw = 0.f, dotsum = 0.f;
    #pragma unroll
    for (int n = 1; n < NA; ++n) {
        float pd = ph[n] - ph[n - 1];
        float x  = pd + PI_F;
        float m  = fmodf(x, TWO_PI);       // python % has sign of divisor
        if (m < 0.f) m += TWO_PI;
        pd = m - PI_F;
        unw += pd;
        dotsum += unw * ((float)n - 7.5f);
    }
    float slope = dotsum / 340.0f;
    float sin_theta = slope / PI_F;        // slope * WAVELENGTH / (2*pi*D), D=0.5, lambda=1
    sin_theta = fminf(1.0f, fmaxf(-1.0f, sin_theta));
    // angle = -asin(sin_theta); steering uses sin(angle) = -sin_theta
    float st = -sin_theta;

    #pragma unroll
    for (int n = 0; n < NA; ++n) {
        float phase = PI_F * st * (float)n;    // 2*pi*D*st*n/lambda = pi*st*n
        table[t * 2 * NA + n]      = cosf(phase);
        table[t * 2 * NA + NA + n] = sinf(phase);
    }
}

__device__ __forceinline__ float dot4(float4 a, float4 b) {
    return a.x * b.x + a.y * b.y + a.z * b.z + a.w * b.w;
}

// launch_bounds(256,4): 4 waves/EU min -> VGPR cap 128. R0 post-mortem: the
// fully-unrolled beam loop hit 256 VGPRs and spilled ~282 MB to scratch
// (WRITE_SIZE evidence); unroll-1 keeps the working set ~80 VGPRs.
__global__ __launch_bounds__(256, 4) void mtl_gains_kernel(const float* __restrict__ W,
                                                           const float* __restrict__ table,
                                                           double* __restrict__ acc, int rows) {
    __shared__ float sh[NBEAM * 2 * NA];   // 384 floats
    for (int i = threadIdx.x; i < NBEAM * 2 * NA; i += blockDim.x) sh[i] = table[i];
    __syncthreads();

    float local = 0.f;
    int tid = blockIdx.x * blockDim.x + threadIdx.x;
    int stride = gridDim.x * blockDim.x;
    #pragma unroll 1
    for (int row = tid; row < rows; row += stride) {
        const float4* wp = (const float4*)(W + (size_t)row * 32);
        float4 w[8];
        #pragma unroll
        for (int i = 0; i < 8; ++i) w[i] = wp[i];

        float minU = 3.4e38f, sumU = 0.f, sumT = 0.f;
        #pragma unroll 1
        for (int j = 0; j < NBEAM; ++j) {
            const float4* tc = (const float4*)(sh + j * 32);
            float re = 0.f, im = 0.f;
            #pragma unroll
            for (int q = 0; q < 4; ++q) {
                float4 c = tc[q], s = tc[q + 4];
                float4 wr = w[q], wi = w[q + 4];
                re += dot4(wr, c) + dot4(wi, s);
                im += dot4(wi, c) - dot4(wr, s);
            }
            float g = sqrtf(re * re + im * im);
            if (j < NUSER) { minU = fminf(minU, g); sumU += g; }
            else           { sumT += g; }
        }
        // comm = -rho*2.5*(min + 0.1*sum) = -2*(min+0.1*sum); sens = -(1-rho)*sumT/4 = -0.05*sumT
        local += -2.0f * (minU + 0.1f * sumU) - 0.05f * sumT;
    }

    // wave reduce (64 lanes)
    #pragma unroll
    for (int off = 32; off > 0; off >>= 1) local += __shfl_down(local, off);
    __shared__ float wsum[4];
    int lane = threadIdx.x & 63, wid = threadIdx.x >> 6;
    if (lane == 0) wsum[wid] = local;
    __syncthreads();
    if (threadIdx.x == 0) {
        float b = wsum[0] + wsum[1] + wsum[2] + wsum[3];
        atomicAdd(acc, (double)b);
    }
}

__global__ void mtl_finalize_kernel(const double* __restrict__ acc, float* __restrict__ out, int rows) {
    if (threadIdx.x == 0) out[0] = (float)(*acc / (double)rows);
}

extern "C" void kernel_launch(void* const* d_in, const int* in_sizes, int n_in,
                              void* d_out, int out_size, void* d_ws, size_t ws_size,
                              hipStream_t stream) {
    const float* W    = (const float*)d_in[0];
    const float* Hc_r = (const float*)d_in[1];
    const float* Hc_i = (const float*)d_in[2];
    const float* Hs_r = (const float*)d_in[3];
    const float* Hs_i = (const float*)d_in[4];
    float* out = (float*)d_out;

    int rows = in_sizes[0] / (2 * NA);   // 2,000,000
    float*  table = (float*)d_ws;
    double* acc   = (double*)((char*)d_ws + ACC_OFFSET);

    mtl_angles_kernel<<<1, 64, 0, stream>>>(Hc_r, Hc_i, Hs_r, Hs_i, table, acc);

    const int ROWS_PER_THREAD = 4;
    int blocks = (rows + 256 * ROWS_PER_THREAD - 1) / (256 * ROWS_PER_THREAD);
    mtl_gains_kernel<<<blocks, 256, 0, stream>>>(W, table, acc, rows);

    mtl_finalize_kernel<<<1, 64, 0, stream>>>(acc, out, rows);
}